// Round 1
// baseline (1293.936 us; speedup 1.0000x reference)
//
#include <hip/hip_runtime.h>
#include <hip/hip_bf16.h>

// ---------------------------------------------------------------------------
// DHN: 2-layer homomorphism-conv GNN
//   layer l: h = act(f) @ [W0|W1|W2] + b   (act = identity for l=0, relu for l=1 input)
//            f' = scatter_add(h[src], dst) per map (3 maps, 64 cols each)
//   pool: segment_sum(relu(f1), batch_idx) -> [64,192]
//   mlp:  relu(pooled@A1+ba1)@A2+ba2 -> [64,10]
// ---------------------------------------------------------------------------

#define BM 64
#define BK 16

// out[:, g*64 : g*64+64] = act(in)[M,K] @ Wg[K,64] + bg ; grid (ceil(M/64), 3)
__global__ void gemm_k64(const float* __restrict__ in, int M, int K,
                         const float* __restrict__ W0, const float* __restrict__ W1,
                         const float* __restrict__ W2,
                         const float* __restrict__ b0, const float* __restrict__ b1,
                         const float* __restrict__ b2,
                         float* __restrict__ out, int reluIn) {
    __shared__ float As[BK][BM + 1];   // [k][m], +1 pad breaks 4-way store conflict
    __shared__ float Ws[BK][64];       // [k][n]

    const int g = blockIdx.y;
    const float* W    = (g == 0) ? W0 : ((g == 1) ? W1 : W2);
    const float* bias = (g == 0) ? b0 : ((g == 1) ? b1 : b2);

    const int m0 = blockIdx.x * BM;
    const int t  = threadIdx.x;          // 0..255
    const int tr = t >> 4;               // 0..15 -> rows tr*4..tr*4+3
    const int tc = t & 15;               // 0..15 -> cols tc*4..tc*4+3

    float acc[4][4] = {};

    for (int k0 = 0; k0 < K; k0 += BK) {
        // --- load A tile: 64 rows x 16 k, float4 per thread ---
        {
            int m  = t >> 2;             // 0..63
            int kq = (t & 3) * 4;        // 0,4,8,12
            int row = m0 + m;
            float4 v = make_float4(0.f, 0.f, 0.f, 0.f);
            if (row < M)
                v = *reinterpret_cast<const float4*>(in + (size_t)row * K + k0 + kq);
            if (reluIn) {
                v.x = fmaxf(v.x, 0.f); v.y = fmaxf(v.y, 0.f);
                v.z = fmaxf(v.z, 0.f); v.w = fmaxf(v.w, 0.f);
            }
            As[kq + 0][m] = v.x; As[kq + 1][m] = v.y;
            As[kq + 2][m] = v.z; As[kq + 3][m] = v.w;
        }
        // --- load W tile: 16 k x 64 n, float4 per thread ---
        {
            int k  = t >> 4;             // 0..15
            int nq = (t & 15) * 4;       // 0..60
            float4 w = *reinterpret_cast<const float4*>(W + (size_t)(k0 + k) * 64 + nq);
            *reinterpret_cast<float4*>(&Ws[k][nq]) = w;
        }
        __syncthreads();
        #pragma unroll
        for (int k = 0; k < BK; ++k) {
            float a[4], w[4];
            #pragma unroll
            for (int i = 0; i < 4; ++i) a[i] = As[k][tr * 4 + i];
            #pragma unroll
            for (int j = 0; j < 4; ++j) w[j] = Ws[k][tc * 4 + j];
            #pragma unroll
            for (int i = 0; i < 4; ++i)
                #pragma unroll
                for (int j = 0; j < 4; ++j)
                    acc[i][j] += a[i] * w[j];
        }
        __syncthreads();
    }

    #pragma unroll
    for (int i = 0; i < 4; ++i) {
        int row = m0 + tr * 4 + i;
        if (row < M) {
            #pragma unroll
            for (int j = 0; j < 4; ++j) {
                int col = tc * 4 + j;
                out[(size_t)row * 192 + g * 64 + col] = acc[i][j] + bias[col];
            }
        }
    }
}

// wave-per-edge gather + atomic scatter. grid (X, 3); lane = feature in [0,64)
__global__ void edge_scatter(const float* __restrict__ h,
                             const int* __restrict__ mpA, const int* __restrict__ mpB,
                             const int* __restrict__ mpC,
                             int E, float* __restrict__ f) {
    const int g = blockIdx.y;
    const int* mp = (g == 0) ? mpA : ((g == 1) ? mpB : mpC);
    const int colOff = g * 64;
    const int lane = threadIdx.x & 63;
    int wid = (blockIdx.x * blockDim.x + threadIdx.x) >> 6;
    const int nw = (gridDim.x * blockDim.x) >> 6;
    for (int e = wid; e < E; e += nw) {
        int dst = mp[e];
        int src = mp[E + e];
        float v = h[(size_t)src * 192 + colOff + lane];
        atomicAdd(f + (size_t)dst * 192 + colOff + lane, v);
    }
}

// segment-pool relu(f) by sorted batch_idx. block = 192 threads (col owner),
// each block scans a 256-row chunk, atomics only at segment boundaries.
__global__ void pool_kernel(const float* __restrict__ f, const int* __restrict__ bidx,
                            int N, float* __restrict__ pooled) {
    const int c  = threadIdx.x;          // 0..191
    const int r0 = blockIdx.x * 256;
    const int r1 = min(r0 + 256, N);
    if (r0 >= N) return;
    float acc = 0.f;
    int cur = bidx[r0];
    for (int r = r0; r < r1; ++r) {
        int b = bidx[r];
        if (b != cur) {
            atomicAdd(&pooled[(size_t)cur * 192 + c], acc);
            acc = 0.f;
            cur = b;
        }
        acc += fmaxf(f[(size_t)r * 192 + c], 0.f);
    }
    atomicAdd(&pooled[(size_t)cur * 192 + c], acc);
}

// per-graph MLP: grid 64 blocks x 256 threads
__global__ void mlp_kernel(const float* __restrict__ pooled,
                           const float* __restrict__ A1, const float* __restrict__ ba1,
                           const float* __restrict__ A2, const float* __restrict__ ba2,
                           float* __restrict__ out) {
    __shared__ float p[192];
    __shared__ float hid[256];
    const int b = blockIdx.x;
    const int t = threadIdx.x;
    if (t < 192) p[t] = pooled[(size_t)b * 192 + t];
    __syncthreads();
    float acc = ba1[t];
    for (int k = 0; k < 192; ++k) acc += p[k] * A1[(size_t)k * 256 + t];
    hid[t] = fmaxf(acc, 0.f);
    __syncthreads();
    if (t < 10) {
        float o = ba2[t];
        for (int k = 0; k < 256; ++k) o += hid[k] * A2[(size_t)k * 10 + t];
        out[(size_t)b * 10 + t] = o;
    }
}

extern "C" void kernel_launch(void* const* d_in, const int* in_sizes, int n_in,
                              void* d_out, int out_size, void* d_ws, size_t ws_size,
                              hipStream_t stream) {
    const float* x      = (const float*)d_in[0];
    const int*   map00  = (const int*)d_in[1];
    const int*   map01  = (const int*)d_in[2];
    const int*   map02  = (const int*)d_in[3];
    const int*   map10  = (const int*)d_in[4];
    const int*   map11  = (const int*)d_in[5];
    const int*   map12  = (const int*)d_in[6];
    const int*   bidx   = (const int*)d_in[7];
    // d_in[8] = batch_size (64, fixed by problem)
    const float* W00 = (const float*)d_in[9];  const float* b00 = (const float*)d_in[10];
    const float* W01 = (const float*)d_in[11]; const float* b01 = (const float*)d_in[12];
    const float* W02 = (const float*)d_in[13]; const float* b02 = (const float*)d_in[14];
    const float* W10 = (const float*)d_in[15]; const float* b10 = (const float*)d_in[16];
    const float* W11 = (const float*)d_in[17]; const float* b11 = (const float*)d_in[18];
    const float* W12 = (const float*)d_in[19]; const float* b12 = (const float*)d_in[20];
    const float* A1  = (const float*)d_in[21]; const float* ba1 = (const float*)d_in[22];
    const float* A2  = (const float*)d_in[23]; const float* ba2 = (const float*)d_in[24];

    const int N = in_sizes[0] / 128;
    const int E = in_sizes[1] / 2;

    float* bufH   = (float*)d_ws;                       // [N,192]
    float* bufF   = bufH + (size_t)N * 192;             // [N,192]
    float* pooled = bufF + (size_t)N * 192;             // [64,192]

    dim3 gemmGrid((N + BM - 1) / BM, 3);
    dim3 scatGrid(2048, 3);

    // layer 0
    gemm_k64<<<gemmGrid, 256, 0, stream>>>(x, N, 128, W00, W01, W02, b00, b01, b02, bufH, 0);
    hipMemsetAsync(bufF, 0, (size_t)N * 192 * sizeof(float), stream);
    edge_scatter<<<scatGrid, 256, 0, stream>>>(bufH, map00, map01, map02, E, bufF);
    // layer 1 (relu fused into A-load)
    gemm_k64<<<gemmGrid, 256, 0, stream>>>(bufF, N, 192, W10, W11, W12, b10, b11, b12, bufH, 1);
    hipMemsetAsync(bufF, 0, (size_t)N * 192 * sizeof(float), stream);
    edge_scatter<<<scatGrid, 256, 0, stream>>>(bufH, map10, map11, map12, E, bufF);
    // pool + mlp
    hipMemsetAsync(pooled, 0, 64 * 192 * sizeof(float), stream);
    pool_kernel<<<(N + 255) / 256, 192, 0, stream>>>(bufF, bidx, N, pooled);
    mlp_kernel<<<64, 256, 0, stream>>>(pooled, A1, ba1, A2, ba2, (float*)d_out);
}

// Round 2
// 1089.973 us; speedup vs baseline: 1.1871x; 1.1871x over previous
//
#include <hip/hip_runtime.h>
#include <hip/hip_bf16.h>

// ---------------------------------------------------------------------------
// DHN 2-layer hom-conv GNN.
// Round 2: replace atomic edge_scatter (614 MB atomic RMW -> 1.7 TB/s, 543us)
// with on-device CSR build + gather-side aggregation (writes drop 16x).
// ---------------------------------------------------------------------------

#define BM 64
#define BK 16

// out[:, g*64 : g*64+64] = act(in)[M,K] @ Wg[K,64] + bg ; grid (ceil(M/64), 3)
__global__ void gemm_k64(const float* __restrict__ in, int M, int K,
                         const float* __restrict__ W0, const float* __restrict__ W1,
                         const float* __restrict__ W2,
                         const float* __restrict__ b0, const float* __restrict__ b1,
                         const float* __restrict__ b2,
                         float* __restrict__ out, int reluIn) {
    __shared__ float As[BK][BM + 1];
    __shared__ float Ws[BK][64];

    const int g = blockIdx.y;
    const float* W    = (g == 0) ? W0 : ((g == 1) ? W1 : W2);
    const float* bias = (g == 0) ? b0 : ((g == 1) ? b1 : b2);

    const int m0 = blockIdx.x * BM;
    const int t  = threadIdx.x;
    const int tr = t >> 4;
    const int tc = t & 15;

    float acc[4][4] = {};

    for (int k0 = 0; k0 < K; k0 += BK) {
        {
            int m  = t >> 2;
            int kq = (t & 3) * 4;
            int row = m0 + m;
            float4 v = make_float4(0.f, 0.f, 0.f, 0.f);
            if (row < M)
                v = *reinterpret_cast<const float4*>(in + (size_t)row * K + k0 + kq);
            if (reluIn) {
                v.x = fmaxf(v.x, 0.f); v.y = fmaxf(v.y, 0.f);
                v.z = fmaxf(v.z, 0.f); v.w = fmaxf(v.w, 0.f);
            }
            As[kq + 0][m] = v.x; As[kq + 1][m] = v.y;
            As[kq + 2][m] = v.z; As[kq + 3][m] = v.w;
        }
        {
            int k  = t >> 4;
            int nq = (t & 15) * 4;
            float4 w = *reinterpret_cast<const float4*>(W + (size_t)(k0 + k) * 64 + nq);
            *reinterpret_cast<float4*>(&Ws[k][nq]) = w;
        }
        __syncthreads();
        #pragma unroll
        for (int k = 0; k < BK; ++k) {
            float a[4], w[4];
            #pragma unroll
            for (int i = 0; i < 4; ++i) a[i] = As[k][tr * 4 + i];
            #pragma unroll
            for (int j = 0; j < 4; ++j) w[j] = Ws[k][tc * 4 + j];
            #pragma unroll
            for (int i = 0; i < 4; ++i)
                #pragma unroll
                for (int j = 0; j < 4; ++j)
                    acc[i][j] += a[i] * w[j];
        }
        __syncthreads();
    }

    #pragma unroll
    for (int i = 0; i < 4; ++i) {
        int row = m0 + tr * 4 + i;
        if (row < M) {
            #pragma unroll
            for (int j = 0; j < 4; ++j) {
                int col = tc * 4 + j;
                out[(size_t)row * 192 + g * 64 + col] = acc[i][j] + bias[col];
            }
        }
    }
}

// ---------------- CSR build (per 3 maps, grid.y = map) ----------------
// rows layout: 3 arrays of (N+1) ints. counts go to rows[g][1+dst].
__global__ void hist_kernel(const int* __restrict__ m0, const int* __restrict__ m1,
                            const int* __restrict__ m2, int E, int* rows, int N) {
    const int g = blockIdx.y;
    const int* mp = (g == 0) ? m0 : ((g == 1) ? m1 : m2);
    int* r = rows + (size_t)g * (N + 1);
    int i = blockIdx.x * blockDim.x + threadIdx.x;
    int stride = gridDim.x * blockDim.x;
    for (int e = i; e < E; e += stride) atomicAdd(&r[1 + mp[e]], 1);
}

// inclusive scan, 256-elem chunks; write chunk totals to partials.
__global__ void scan_partial(int* rows, int R, int* partials, int nchunk) {
    const int g = blockIdx.y;
    int* r = rows + (size_t)g * R;
    __shared__ int sm[256];
    int idx = blockIdx.x * 256 + threadIdx.x;
    int v = (idx < R) ? r[idx] : 0;
    sm[threadIdx.x] = v;
    __syncthreads();
    for (int off = 1; off < 256; off <<= 1) {
        int t = (threadIdx.x >= off) ? sm[threadIdx.x - off] : 0;
        __syncthreads();
        sm[threadIdx.x] += t;
        __syncthreads();
    }
    if (idx < R) r[idx] = sm[threadIdx.x];
    if (threadIdx.x == 255) partials[g * nchunk + blockIdx.x] = sm[255];
}

// add scanned chunk offsets. grid (1, 3), block 256. nchunk <= 256.
__global__ void scan_apply(int* rows, int R, const int* __restrict__ partials, int nchunk) {
    const int g = blockIdx.y;
    int* r = rows + (size_t)g * R;
    __shared__ int offs[256];
    if (threadIdx.x == 0) {
        int run = 0;
        for (int c = 0; c < nchunk; ++c) { offs[c] = run; run += partials[g * nchunk + c]; }
    }
    __syncthreads();
    for (int idx = 256 + threadIdx.x; idx < R; idx += 256)
        r[idx] += offs[idx >> 8];
}

// scatter src indices into per-dst slots; rows[g][n] becomes END of node n.
__global__ void fill_kernel(const int* __restrict__ m0, const int* __restrict__ m1,
                            const int* __restrict__ m2, int E, int* rows, int N,
                            int* cols) {
    const int g = blockIdx.y;
    const int* mp = (g == 0) ? m0 : ((g == 1) ? m1 : m2);
    int* r = rows + (size_t)g * (N + 1);
    int* cl = cols + (size_t)g * E;
    int i = blockIdx.x * blockDim.x + threadIdx.x;
    int stride = gridDim.x * blockDim.x;
    for (int e = i; e < E; e += stride) {
        int dst = mp[e];
        int src = mp[E + e];
        int pos = atomicAdd(&r[dst], 1);
        cl[pos] = src;
    }
}

// one wave per (node, map); lane = feature. No atomics, coalesced 256B store.
__global__ void csr_agg(const float* __restrict__ h, const int* __restrict__ rows,
                        const int* __restrict__ cols, int N, int E,
                        float* __restrict__ f) {
    const int g = blockIdx.y;
    const int lane = threadIdx.x & 63;
    int n = (blockIdx.x * blockDim.x + threadIdx.x) >> 6;
    if (n >= N) return;
    const int* r  = rows + (size_t)g * (N + 1);
    const int* cl = cols + (size_t)g * E;
    int s = (n == 0) ? 0 : r[n - 1];
    int e = r[n];
    const float* hg = h + g * 64 + lane;
    float acc = 0.f;
    int i = s;
    for (; i + 1 < e; i += 2) {
        int s0 = cl[i], s1 = cl[i + 1];
        float v0 = hg[(size_t)s0 * 192];
        float v1 = hg[(size_t)s1 * 192];
        acc += v0 + v1;
    }
    if (i < e) acc += hg[(size_t)cl[i] * 192];
    f[(size_t)n * 192 + g * 64 + lane] = acc;
}

// segment-pool relu(f) by sorted batch_idx.
__global__ void pool_kernel(const float* __restrict__ f, const int* __restrict__ bidx,
                            int N, float* __restrict__ pooled) {
    const int c  = threadIdx.x;          // 0..191
    const int r0 = blockIdx.x * 256;
    const int r1 = min(r0 + 256, N);
    if (r0 >= N) return;
    float acc = 0.f;
    int cur = bidx[r0];
    for (int r = r0; r < r1; ++r) {
        int b = bidx[r];
        if (b != cur) {
            atomicAdd(&pooled[(size_t)cur * 192 + c], acc);
            acc = 0.f;
            cur = b;
        }
        acc += fmaxf(f[(size_t)r * 192 + c], 0.f);
    }
    atomicAdd(&pooled[(size_t)cur * 192 + c], acc);
}

__global__ void mlp_kernel(const float* __restrict__ pooled,
                           const float* __restrict__ A1, const float* __restrict__ ba1,
                           const float* __restrict__ A2, const float* __restrict__ ba2,
                           float* __restrict__ out) {
    __shared__ float p[192];
    __shared__ float hid[256];
    const int b = blockIdx.x;
    const int t = threadIdx.x;
    if (t < 192) p[t] = pooled[(size_t)b * 192 + t];
    __syncthreads();
    float acc = ba1[t];
    for (int k = 0; k < 192; ++k) acc += p[k] * A1[(size_t)k * 256 + t];
    hid[t] = fmaxf(acc, 0.f);
    __syncthreads();
    if (t < 10) {
        float o = ba2[t];
        for (int k = 0; k < 256; ++k) o += hid[k] * A2[(size_t)k * 10 + t];
        out[(size_t)b * 10 + t] = o;
    }
}

extern "C" void kernel_launch(void* const* d_in, const int* in_sizes, int n_in,
                              void* d_out, int out_size, void* d_ws, size_t ws_size,
                              hipStream_t stream) {
    const float* x      = (const float*)d_in[0];
    const int*   map00  = (const int*)d_in[1];
    const int*   map01  = (const int*)d_in[2];
    const int*   map02  = (const int*)d_in[3];
    const int*   map10  = (const int*)d_in[4];
    const int*   map11  = (const int*)d_in[5];
    const int*   map12  = (const int*)d_in[6];
    const int*   bidx   = (const int*)d_in[7];
    const float* W00 = (const float*)d_in[9];  const float* b00 = (const float*)d_in[10];
    const float* W01 = (const float*)d_in[11]; const float* b01 = (const float*)d_in[12];
    const float* W02 = (const float*)d_in[13]; const float* b02 = (const float*)d_in[14];
    const float* W10 = (const float*)d_in[15]; const float* b10 = (const float*)d_in[16];
    const float* W11 = (const float*)d_in[17]; const float* b11 = (const float*)d_in[18];
    const float* W12 = (const float*)d_in[19]; const float* b12 = (const float*)d_in[20];
    const float* A1  = (const float*)d_in[21]; const float* ba1 = (const float*)d_in[22];
    const float* A2  = (const float*)d_in[23]; const float* ba2 = (const float*)d_in[24];

    const int N = in_sizes[0] / 128;
    const int E = in_sizes[1] / 2;
    const int R = N + 1;
    const int nchunk = (R + 255) / 256;

    float* bufH   = (float*)d_ws;                       // [N,192]
    float* bufF   = bufH + (size_t)N * 192;             // [N,192]
    float* pooled = bufF + (size_t)N * 192;             // [64,192]
    int*   rows     = (int*)(pooled + 64 * 192);        // 3*(N+1)
    int*   cols     = rows + (size_t)3 * R;             // 3*E
    int*   partials = cols + (size_t)3 * E;             // 3*nchunk

    dim3 gemmGrid((N + BM - 1) / BM, 3);
    dim3 edgeGrid(1024, 3);
    dim3 scanPGrid(nchunk, 3);
    dim3 scanAGrid(1, 3);
    dim3 aggGrid((N + 3) / 4, 3);

    // ---- layer 0 ----
    gemm_k64<<<gemmGrid, 256, 0, stream>>>(x, N, 128, W00, W01, W02, b00, b01, b02, bufH, 0);
    hipMemsetAsync(rows, 0, (size_t)3 * R * sizeof(int), stream);
    hist_kernel<<<edgeGrid, 256, 0, stream>>>(map00, map01, map02, E, rows, N);
    scan_partial<<<scanPGrid, 256, 0, stream>>>(rows, R, partials, nchunk);
    scan_apply<<<scanAGrid, 256, 0, stream>>>(rows, R, partials, nchunk);
    fill_kernel<<<edgeGrid, 256, 0, stream>>>(map00, map01, map02, E, rows, N, cols);
    csr_agg<<<aggGrid, 256, 0, stream>>>(bufH, rows, cols, N, E, bufF);

    // ---- layer 1 ----
    gemm_k64<<<gemmGrid, 256, 0, stream>>>(bufF, N, 192, W10, W11, W12, b10, b11, b12, bufH, 1);
    hipMemsetAsync(rows, 0, (size_t)3 * R * sizeof(int), stream);
    hist_kernel<<<edgeGrid, 256, 0, stream>>>(map10, map11, map12, E, rows, N);
    scan_partial<<<scanPGrid, 256, 0, stream>>>(rows, R, partials, nchunk);
    scan_apply<<<scanAGrid, 256, 0, stream>>>(rows, R, partials, nchunk);
    fill_kernel<<<edgeGrid, 256, 0, stream>>>(map10, map11, map12, E, rows, N, cols);
    csr_agg<<<aggGrid, 256, 0, stream>>>(bufH, rows, cols, N, E, bufF);

    // ---- pool + mlp ----
    hipMemsetAsync(pooled, 0, 64 * 192 * sizeof(float), stream);
    pool_kernel<<<(N + 255) / 256, 192, 0, stream>>>(bufF, bidx, N, pooled);
    mlp_kernel<<<64, 256, 0, stream>>>(pooled, A1, ba1, A2, ba2, (float*)d_out);
}